// Round 5
// baseline (5591.664 us; speedup 1.0000x reference)
//
#include <hip/hip_runtime.h>
#include <math.h>

#define NHW 65536
#define PADM 1792           // float2 stride for xf/of rows (1764 padded)
#define PI2 6.283185307179586f

__device__ __forceinline__ float gelu_f(float v) {
    return 0.5f * v * (1.0f + erff(v * 0.7071067811865476f));
}

// ---------------------------------------------------------------- tables
// D1[n][2k]=cos(2pi k n/256), D1[n][2k+1]=-sin  (forward W-DFT, 48 modes padded)
// T1c/T1s[n*48+k], T2c/T2s[k*256+n] = cos/sin(2pi k n/256)
__global__ void k_tables(float* __restrict__ D1, float* __restrict__ T1c, float* __restrict__ T1s,
                         float* __restrict__ T2c, float* __restrict__ T2s) {
    int idx = blockIdx.x * 256 + threadIdx.x;
    if (idx < 256 * 48) {
        int n = idx / 48, k = idx % 48;
        float ang = PI2 * (float)((n * k) & 255) / 256.0f;
        float s, c;
        sincosf(ang, &s, &c);
        D1[n * 96 + 2 * k] = c;
        D1[n * 96 + 2 * k + 1] = -s;
        T1c[n * 48 + k] = c;
        T1s[n * 48 + k] = s;
    }
    if (idx < 42 * 256) {
        int k = idx / 256, n = idx % 256;
        float ang = PI2 * (float)((n * k) & 255) / 256.0f;
        float s, c;
        sincosf(ang, &s, &c);
        T2c[idx] = c;
        T2s[idx] = s;
    }
}

__global__ void k_nrm_init(float2* __restrict__ nrm, int n) {
    int i = blockIdx.x * 256 + threadIdx.x;
    if (i < n) nrm[i] = make_float2(1.0f, 0.0f);
}

// ---------------------------------------------------------------- in-proj (writes RAW affine; gelu is applied on read)
__global__ void __launch_bounds__(256) k_in(const float* __restrict__ up, const float* __restrict__ noise,
                                            const float* __restrict__ w, const float* __restrict__ bias,
                                            float* __restrict__ A, int b0) {
    __shared__ float ws_[96 * 6];
    __shared__ float bs_[96];
    int t = threadIdx.x;
    for (int i = t; i < 96 * 6; i += 256) ws_[i] = w[i];
    if (t < 96) bs_[t] = bias[t];
    __syncthreads();
    int br = blockIdx.x >> 8, h = blockIdx.x & 255;
    int b = b0 + br;
    float v0 = up[((size_t)(b * 3 + 0) * 256 + h) * 256 + t];
    float v1 = up[((size_t)(b * 3 + 1) * 256 + h) * 256 + t];
    float v2 = up[((size_t)(b * 3 + 2) * 256 + h) * 256 + t];
    float v3 = noise[((size_t)b * 256 + h) * 256 + t];
    float v4 = -1.0f + 2.0f * (float)t / 255.0f;
    float v5 = -1.0f + 2.0f * (float)h / 255.0f;
    size_t base = (size_t)br * 96 * NHW + (size_t)h * 256 + t;
    for (int o = 0; o < 96; o++) {
        const float* wo = ws_ + o * 6;
        float acc = bs_[o];
        acc = fmaf(v0, wo[0], acc); acc = fmaf(v1, wo[1], acc); acc = fmaf(v2, wo[2], acc);
        acc = fmaf(v3, wo[3], acc); acc = fmaf(v4, wo[4], acc); acc = fmaf(v5, wo[5], acc);
        A[base + (size_t)o * NHW] = acc;   // raw; norm starts as identity
    }
}

// ---------------------------------------------------------------- S1: forward W-DFT (act on load)
// rz[row][col] , row=(bc)*256+h, col=2k(+1), k<42
__global__ void __launch_bounds__(256) k_s1(const float* __restrict__ A, const float2* __restrict__ nrm,
                                            const float* __restrict__ D1, float* __restrict__ rz) {
    __shared__ float Xl[32][132];  // [k][row]
    __shared__ float Dl[32][100];  // [k][col]
    int t = threadIdx.x;
    int row0 = blockIdx.x * 128;
    int bc = blockIdx.x >> 1;           // 128 rows all within one (b,c) plane
    float2 nv = nrm[bc];
    int tn = t % 16, tm = t / 16;
    int r0 = tn * 8, c0 = tm * 6;
    float acc[8][6] = {};
    for (int kc = 0; kc < 256; kc += 32) {
        __syncthreads();
#pragma unroll
        for (int it = 0; it < 4; it++) {
            int slot = t + 256 * it;
            int r = slot >> 3, j4 = (slot & 7) * 4;
            float4 g = *(const float4*)&A[(size_t)(row0 + r) * 256 + kc + j4];
            Xl[j4 + 0][r] = gelu_f(fmaf(g.x, nv.x, nv.y));
            Xl[j4 + 1][r] = gelu_f(fmaf(g.y, nv.x, nv.y));
            Xl[j4 + 2][r] = gelu_f(fmaf(g.z, nv.x, nv.y));
            Xl[j4 + 3][r] = gelu_f(fmaf(g.w, nv.x, nv.y));
        }
#pragma unroll
        for (int it = 0; it < 3; it++) {
            int slot = t + 256 * it;
            int rr = slot / 24, c4 = (slot % 24) * 4;
            *(float4*)&Dl[rr][c4] = *(const float4*)&D1[(size_t)(kc + rr) * 96 + c4];
        }
        __syncthreads();
        for (int k = 0; k < 32; k++) {
            float a[8], d[6];
#pragma unroll
            for (int i = 0; i < 8; i++) a[i] = Xl[k][r0 + i];
#pragma unroll
            for (int j = 0; j < 6; j++) d[j] = Dl[k][c0 + j];
#pragma unroll
            for (int i = 0; i < 8; i++)
#pragma unroll
                for (int j = 0; j < 6; j++) acc[i][j] = fmaf(a[i], d[j], acc[i][j]);
        }
    }
#pragma unroll
    for (int i = 0; i < 8; i++) {
        size_t row = row0 + r0 + i;
#pragma unroll
        for (int j = 0; j < 6; j++) {
            int col = c0 + j;
            if (col < 84) rz[row * 84 + col] = acc[i][j];
        }
    }
}

// ---------------------------------------------------------------- S2: forward H-DFT
// xf[bc][kh*42+kw] (float2, row stride PADM)
__global__ void __launch_bounds__(256) k_s2(const float* __restrict__ r1, const float* __restrict__ T1c,
                                            const float* __restrict__ T1s, float* __restrict__ xf) {
    int bc = blockIdx.x;
    int t = threadIdx.x;
    __shared__ float rl[32][88];
    __shared__ float tcl[32][48], tsl[32][48];
    int tkh = t / 11, tkw = t % 11;
    bool act = (t < 231);
    int kh0 = tkh * 2, kw0 = tkw * 4;
    float accr[2][4] = {}, acci[2][4] = {};
    const float* rp = r1 + (size_t)bc * 256 * 84;
    for (int hc = 0; hc < 256; hc += 32) {
        __syncthreads();
        for (int f = t; f < 32 * 88; f += 256) {
            int hl = f / 88, m = f % 88;
            rl[hl][m] = (m < 84) ? rp[(size_t)(hc + hl) * 84 + m] : 0.f;
        }
        for (int f = t; f < 32 * 48; f += 256) {
            int hl = f / 48, k = f % 48;
            tcl[hl][k] = T1c[(hc + hl) * 48 + k];
            tsl[hl][k] = T1s[(hc + hl) * 48 + k];
        }
        __syncthreads();
        if (act) {
            for (int hl = 0; hl < 32; hl++) {
                float c0 = tcl[hl][kh0], s0 = tsl[hl][kh0];
                float c1 = tcl[hl][kh0 + 1], s1v = tsl[hl][kh0 + 1];
#pragma unroll
                for (int j = 0; j < 4; j++) {
                    float arr = rl[hl][(kw0 + j) * 2], aii = rl[hl][(kw0 + j) * 2 + 1];
                    accr[0][j] = fmaf(arr, c0, fmaf(aii, s0, accr[0][j]));
                    acci[0][j] = fmaf(aii, c0, fmaf(-arr, s0, acci[0][j]));
                    accr[1][j] = fmaf(arr, c1, fmaf(aii, s1v, accr[1][j]));
                    acci[1][j] = fmaf(aii, c1, fmaf(-arr, s1v, acci[1][j]));
                }
            }
        }
    }
    if (act) {
        float* xp = xf + (size_t)bc * (PADM * 2);
#pragma unroll
        for (int i = 0; i < 2; i++)
#pragma unroll
            for (int j = 0; j < 4; j++) {
                int kw = kw0 + j;
                if (kw < 42) {
                    xp[((kh0 + i) * 42 + kw) * 2] = accr[i][j];
                    xp[((kh0 + i) * 42 + kw) * 2 + 1] = acci[i][j];
                }
            }
    }
}

// ---------------------------------------------------------------- S3: per-mode channel mix, native spec_w layout
// of[b*96+o][m] = sum_i xf[b*96+i][m] * w[(i*96+o)][m]   (complex; m-major, coalesced)
__global__ void __launch_bounds__(256) k_s3(const float* __restrict__ xfb, const float* __restrict__ sw,
                                            float* __restrict__ ofb, int nbc) {
    int bx = blockIdx.x;
    int b = bx % nbc, mt = bx / nbc;
    int m0 = mt * 16;
    int t = threadIdx.x;
    __shared__ float2 xl[96][16];
    const float2* xx = (const float2*)xfb;
    for (int f = t; f < 1536; f += 256) {
        int i = f >> 4, ml = f & 15;
        int m = m0 + ml;
        float2 v = make_float2(0.f, 0.f);
        if (m < 1764) v = xx[(size_t)(b * 96 + i) * PADM + m];
        xl[i][ml] = v;
    }
    __syncthreads();
    int ml = t & 15, og = t >> 4;
    int m = m0 + ml;
    if (m >= 1764) return;
    float accr[6] = {}, acci[6] = {};
    const float2* wp = (const float2*)sw;
    for (int i = 0; i < 96; i++) {
        float2 xv = xl[i][ml];
#pragma unroll
        for (int j = 0; j < 6; j++) {
            int o = og * 6 + j;
            float2 wv = wp[(size_t)(i * 96 + o) * 1764 + m];
            accr[j] = fmaf(xv.x, wv.x, fmaf(-xv.y, wv.y, accr[j]));
            acci[j] = fmaf(xv.x, wv.y, fmaf(xv.y, wv.x, acci[j]));
        }
    }
    float2* op = (float2*)ofb;
#pragma unroll
    for (int j = 0; j < 6; j++) {
        int o = og * 6 + j;
        op[(size_t)(b * 96 + o) * PADM + m] = make_float2(accr[j], acci[j]);
    }
}

// ---------------------------------------------------------------- dense 1x1 conv (act on load), writes B raw
__global__ void __launch_bounds__(256) k_dense(const float* __restrict__ A, const float2* __restrict__ nrm,
                                               const float* __restrict__ dw, const float* __restrict__ db,
                                               float* __restrict__ B) {
    __shared__ float Xl[32][132];
    __shared__ float Wl[32][100];
    __shared__ float bs[96];
    __shared__ float2 ns[96];
    int t = threadIdx.x;
    int p0 = blockIdx.x * 128;
    int b = blockIdx.y;
    if (t < 96) { bs[t] = db[t]; ns[t] = nrm[b * 96 + t]; }
    int tn = t % 16, tm = t / 16;
    int n0 = tn * 8, m0 = tm * 6;
    float acc[8][6] = {};
    const float* xb = A + (size_t)b * 96 * NHW;
    for (int kc = 0; kc < 96; kc += 32) {
        __syncthreads();
#pragma unroll
        for (int it = 0; it < 4; it++) {
            int slot = t + 256 * it;
            int k = slot >> 5, j4 = (slot & 31) * 4;
            float4 g = *(const float4*)&xb[(size_t)(kc + k) * NHW + p0 + j4];
            float2 nv = ns[kc + k];
            Xl[k][j4 + 0] = gelu_f(fmaf(g.x, nv.x, nv.y));
            Xl[k][j4 + 1] = gelu_f(fmaf(g.y, nv.x, nv.y));
            Xl[k][j4 + 2] = gelu_f(fmaf(g.z, nv.x, nv.y));
            Xl[k][j4 + 3] = gelu_f(fmaf(g.w, nv.x, nv.y));
        }
#pragma unroll
        for (int it = 0; it < 3; it++) {
            int slot = t + 256 * it;
            int o = slot >> 3, j4 = (slot & 7) * 4;
            float4 g = *(const float4*)&dw[(size_t)o * 96 + kc + j4];
            Wl[j4 + 0][o] = g.x; Wl[j4 + 1][o] = g.y; Wl[j4 + 2][o] = g.z; Wl[j4 + 3][o] = g.w;
        }
        __syncthreads();
        for (int k = 0; k < 32; k++) {
            float a[8], wv[6];
#pragma unroll
            for (int i = 0; i < 8; i++) a[i] = Xl[k][n0 + i];
#pragma unroll
            for (int j = 0; j < 6; j++) wv[j] = Wl[k][m0 + j];
#pragma unroll
            for (int i = 0; i < 8; i++)
#pragma unroll
                for (int j = 0; j < 6; j++) acc[i][j] = fmaf(a[i], wv[j], acc[i][j]);
        }
    }
#pragma unroll
    for (int j = 0; j < 6; j++) {
        int o = m0 + j;
        float bv = bs[o];
        float* tp = B + ((size_t)b * 96 + o) * NHW + p0 + n0;
#pragma unroll
        for (int i = 0; i < 8; i++) tp[i] = acc[i][j] + bv;
    }
}

// ---------------------------------------------------------------- S5: inverse-H (fused) + inverse-W + depthwise
//  + residual; reads A (act on load) and B (dense), writes val in-place into B; per-(b,c) stats -> ps
__global__ void __launch_bounds__(256) k_s5(const float* __restrict__ A, const float2* __restrict__ nrm,
                                            float* __restrict__ B, const float* __restrict__ ofb,
                                            const float* __restrict__ T2c, const float* __restrict__ T2s,
                                            const float* __restrict__ lw, const float* __restrict__ lb,
                                            float2* __restrict__ ps) {
    int bo = blockIdx.x;
    int o = bo % 96;
    int t = threadIdx.x;  // = w
    __shared__ float ofl[3528];
    __shared__ float xr[10][258];
    __shared__ float zl[8][84];
    __shared__ float rs1[4], rs2[4];
    float2 nv = nrm[bo];
    float Tc[42], Ts[42];
#pragma unroll
    for (int k = 0; k < 42; k++) { Tc[k] = T2c[k * 256 + t]; Ts[k] = T2s[k * 256 + t]; }
    float l9[9];
#pragma unroll
    for (int j = 0; j < 9; j++) l9[j] = lw[o * 9 + j];
    float lbv = lb[o];
    const float* xp = A + (size_t)bo * NHW;
    float* tp = B + (size_t)bo * NHW;
    const float* op_ = ofb + (size_t)bo * (PADM * 2);
    for (int f = t; f < 3528; f += 256) ofl[f] = op_[f];
    float s1 = 0.f, s2 = 0.f;
    for (int hc = 0; hc < 256; hc += 8) {
        __syncthreads();
        // halo tile of activations (act applied on load)
        for (int f = t; f < 2580; f += 256) {
            int j = f / 258, cc = f % 258;
            int hr = hc - 1 + j, wc = cc - 1;
            float v = 0.f;
            if (hr >= 0 && hr < 256 && wc >= 0 && wc < 256)
                v = gelu_f(fmaf(xp[(size_t)hr * 256 + wc], nv.x, nv.y));
            xr[j][cc] = v;
        }
        // fused inverse-H: zl[hl][kw] from of
        for (int e = t; e < 336; e += 256) {
            int hl = e / 42, kw = e % 42;
            int h = hc + hl;
            float zr = 0.f, zi = 0.f;
            for (int kh = 0; kh < 42; kh++) {
                float c = T2c[kh * 256 + h], s = T2s[kh * 256 + h];
                float2 ov = *(const float2*)&ofl[(kh * 42 + kw) * 2];
                zr = fmaf(ov.x, c, fmaf(-ov.y, s, zr));
                zi = fmaf(ov.x, s, fmaf(ov.y, c, zi));
            }
            float fsc = (kw == 0) ? (1.0f / 65536.0f) : (2.0f / 65536.0f);
            zl[hl][2 * kw] = zr * fsc;
            zl[hl][2 * kw + 1] = zi * fsc;
        }
        __syncthreads();
#pragma unroll 1
        for (int hl = 0; hl < 8; hl++) {
            int h = hc + hl;
            float acc = 0.f;
#pragma unroll
            for (int k = 0; k < 42; k++) {
                acc = fmaf(zl[hl][2 * k], Tc[k], acc);
                acc = fmaf(-zl[hl][2 * k + 1], Ts[k], acc);
            }
            float dv = tp[(size_t)h * 256 + t];
            float dwv = lbv;
#pragma unroll
            for (int a = 0; a < 3; a++)
#pragma unroll
                for (int bq = 0; bq < 3; bq++) dwv = fmaf(xr[hl + a][t + bq], l9[a * 3 + bq], dwv);
            float xc = xr[hl + 1][t + 1];
            float val = xc + 0.5f * (acc + dv + dwv);
            tp[(size_t)h * 256 + t] = val;
            s1 += val;
            s2 = fmaf(val, val, s2);
        }
    }
    for (int off2 = 32; off2 > 0; off2 >>= 1) {
        s1 += __shfl_down(s1, off2);
        s2 += __shfl_down(s2, off2);
    }
    int wid = t >> 6, lane = t & 63;
    if (lane == 0) { rs1[wid] = s1; rs2[wid] = s2; }
    __syncthreads();
    if (t == 0) ps[bo] = make_float2(rs1[0] + rs1[1] + rs1[2] + rs1[3], rs2[0] + rs2[1] + rs2[2] + rs2[3]);
}

// ---------------------------------------------------------------- stats -> per-channel affine (sc, sh)
__global__ void k_stats(const float2* __restrict__ ps, const float* __restrict__ ng,
                        const float* __restrict__ nb, float2* __restrict__ nrm, int n) {
    int i = blockIdx.x * 64 + threadIdx.x;
    if (i >= n) return;
    int c = i % 96, b = i / 96, g = c >> 4;
    float s = 0.f, q = 0.f;
#pragma unroll
    for (int j = 0; j < 16; j++) { float2 v = ps[b * 96 + g * 16 + j]; s += v.x; q += v.y; }
    const float inv_n = 1.0f / 1048576.0f;
    float mean = s * inv_n;
    float var = q * inv_n - mean * mean;
    float rstd = rsqrtf(var + 1e-5f);
    float sc = rstd * ng[c];
    nrm[i] = make_float2(sc, nb[c] - mean * sc);
}

// ---------------------------------------------------------------- out-proj + clip (act on load)
__global__ void __launch_bounds__(256) k_out(const float* __restrict__ A, const float2* __restrict__ nrm,
                                             const float* __restrict__ up, const float* __restrict__ opw,
                                             const float* __restrict__ opb, float* __restrict__ out, int b0) {
    __shared__ float wl[288];
    __shared__ float2 nl[96];
    int t = threadIdx.x;
    int br = blockIdx.x >> 8;
    if (t < 96) nl[t] = nrm[br * 96 + t];
    for (int f = t; f < 288; f += 256) wl[f] = opw[f];
    __syncthreads();
    int p = (blockIdx.x & 255) * 256 + t;
    const float* xp = A + (size_t)br * 96 * NHW + p;
    float a0 = opb[0], a1 = opb[1], a2 = opb[2];
    for (int i = 0; i < 96; i++) {
        float2 nv = nl[i];
        float xv = gelu_f(fmaf(xp[(size_t)i * NHW], nv.x, nv.y));
        a0 = fmaf(xv, wl[i], a0);
        a1 = fmaf(xv, wl[96 + i], a1);
        a2 = fmaf(xv, wl[192 + i], a2);
    }
    int b = b0 + br;
#pragma unroll
    for (int o = 0; o < 3; o++) {
        float av = (o == 0) ? a0 : ((o == 1) ? a1 : a2);
        size_t idx = ((size_t)b * 3 + o) * NHW + p;
        float v = up[idx] + av;
        out[idx] = fminf(fmaxf(v, 0.0f), 1.0f);
    }
}

extern "C" void kernel_launch(void* const* d_in, const int* in_sizes, int n_in,
                              void* d_out, int out_size, void* d_ws, size_t ws_size,
                              hipStream_t stream) {
    const float* up = (const float*)d_in[0];
    const float* noise = (const float*)d_in[1];
    const float* ipw = (const float*)d_in[2];
    const float* ipb = (const float*)d_in[3];
    const float* specw = (const float*)d_in[4];
    const float* dw = (const float*)d_in[5];
    const float* db = (const float*)d_in[6];
    const float* lw = (const float*)d_in[7];
    const float* lb = (const float*)d_in[8];
    const float* ng = (const float*)d_in[9];
    const float* nb = (const float*)d_in[10];
    const float* opw = (const float*)d_in[11];
    const float* opb = (const float*)d_in[12];
    float* out = (float*)d_out;

    // adaptive batch chunking: footprint(nbc) in floats
    auto needf = [](size_t nbc) -> size_t {
        return nbc * (2ull * 6291456 + 2064384 + 2ull * 344064 + 3ull * 192) + 70656ull;
    };
    int nbc = 8;
    while (nbc > 1 && needf(nbc) * 4ull > ws_size) nbc >>= 1;
    if (needf(nbc) * 4ull > ws_size) return;  // even 1-batch doesn't fit: fail visibly

    float* ws = (float*)d_ws;
    float* A0  = ws;                               // nbc*6291456
    float* B0  = A0 + (size_t)nbc * 6291456;       // nbc*6291456
    float* rz  = B0 + (size_t)nbc * 6291456;       // nbc*2064384
    float* xfb = rz + (size_t)nbc * 2064384;       // nbc*344064 (96 rows * PADM f2)
    float* ofb = xfb + (size_t)nbc * 344064;       // nbc*344064
    float* ps  = ofb + (size_t)nbc * 344064;       // nbc*192
    float* nrm0 = ps + (size_t)nbc * 192;          // nbc*192
    float* nrm1 = nrm0 + (size_t)nbc * 192;        // nbc*192
    float* D1  = nrm1 + (size_t)nbc * 192;         // 24576
    float* T1c = D1 + 24576;                       // 12288
    float* T1s = T1c + 12288;                      // 12288
    float* T2c = T1s + 12288;                      // 10752
    float* T2s = T2c + 10752;                      // 10752

    k_tables<<<48, 256, 0, stream>>>(D1, T1c, T1s, T2c, T2s);

    for (int b0 = 0; b0 < 8; b0 += nbc) {
        k_nrm_init<<<(nbc * 96 + 255) / 256, 256, 0, stream>>>((float2*)nrm0, nbc * 96);
        k_in<<<nbc * 256, 256, 0, stream>>>(up, noise, ipw, ipb, A0, b0);
        float *A = A0, *B = B0, *nc = nrm0, *nn = nrm1;
        for (int l = 0; l < 4; l++) {
            k_s1<<<nbc * 192, 256, 0, stream>>>(A, (const float2*)nc, D1, rz);
            k_s2<<<nbc * 96, 256, 0, stream>>>(rz, T1c, T1s, xfb);
            k_s3<<<111 * nbc, 256, 0, stream>>>(xfb, specw, ofb, nbc);
            k_dense<<<dim3(512, nbc), 256, 0, stream>>>(A, (const float2*)nc,
                                                        dw + (size_t)l * 9216, db + (size_t)l * 96, B);
            k_s5<<<nbc * 96, 256, 0, stream>>>(A, (const float2*)nc, B, ofb, T2c, T2s,
                                               lw + (size_t)l * 864, lb + (size_t)l * 96, (float2*)ps);
            k_stats<<<(nbc * 96 + 63) / 64, 64, 0, stream>>>((const float2*)ps, ng + (size_t)l * 96,
                                                             nb + (size_t)l * 96, (float2*)nn, nbc * 96);
            float* tA = A; A = B; B = tA;
            float* tN = nc; nc = nn; nn = tN;
        }
        k_out<<<nbc * 256, 256, 0, stream>>>(A, (const float2*)nc, up, opw, opb, out, b0);
    }
}

// Round 6
// 4536.831 us; speedup vs baseline: 1.2325x; 1.2325x over previous
//
#include <hip/hip_runtime.h>
#include <math.h>

#define NHW 65536
#define PADM 1792           // float2 stride for xf/of rows (1764 padded)
#define PI2 6.283185307179586f

__device__ __forceinline__ float gelu_f(float v) {
    return 0.5f * v * (1.0f + erff(v * 0.7071067811865476f));
}

// ---------------------------------------------------------------- tables
// D1[n][2k]=cos(2pi k n/256), D1[n][2k+1]=-sin  (forward W-DFT, 48 modes padded)
// T1c/T1s[n*48+k], T2c/T2s[k*256+n] = cos/sin(2pi k n/256)
__global__ void k_tables(float* __restrict__ D1, float* __restrict__ T1c, float* __restrict__ T1s,
                         float* __restrict__ T2c, float* __restrict__ T2s) {
    int idx = blockIdx.x * 256 + threadIdx.x;
    if (idx < 256 * 48) {
        int n = idx / 48, k = idx % 48;
        float ang = PI2 * (float)((n * k) & 255) / 256.0f;
        float s, c;
        sincosf(ang, &s, &c);
        D1[n * 96 + 2 * k] = c;
        D1[n * 96 + 2 * k + 1] = -s;
        T1c[n * 48 + k] = c;
        T1s[n * 48 + k] = s;
    }
    if (idx < 42 * 256) {
        int k = idx / 256, n = idx % 256;
        float ang = PI2 * (float)((n * k) & 255) / 256.0f;
        float s, c;
        sincosf(ang, &s, &c);
        T2c[idx] = c;
        T2s[idx] = s;
    }
}

// ---------------------------------------------------------------- in-proj (writes ACTIVATED x directly)
__global__ void __launch_bounds__(256) k_in(const float* __restrict__ up, const float* __restrict__ noise,
                                            const float* __restrict__ w, const float* __restrict__ bias,
                                            float* __restrict__ X, int b0) {
    __shared__ float ws_[96 * 6];
    __shared__ float bs_[96];
    int t = threadIdx.x;
    for (int i = t; i < 96 * 6; i += 256) ws_[i] = w[i];
    if (t < 96) bs_[t] = bias[t];
    __syncthreads();
    int br = blockIdx.x >> 8, h = blockIdx.x & 255;
    int b = b0 + br;
    float v0 = up[((size_t)(b * 3 + 0) * 256 + h) * 256 + t];
    float v1 = up[((size_t)(b * 3 + 1) * 256 + h) * 256 + t];
    float v2 = up[((size_t)(b * 3 + 2) * 256 + h) * 256 + t];
    float v3 = noise[((size_t)b * 256 + h) * 256 + t];
    float v4 = -1.0f + 2.0f * (float)t / 255.0f;
    float v5 = -1.0f + 2.0f * (float)h / 255.0f;
    size_t base = (size_t)br * 96 * NHW + (size_t)h * 256 + t;
    for (int o = 0; o < 96; o++) {
        const float* wo = ws_ + o * 6;
        float acc = bs_[o];
        acc = fmaf(v0, wo[0], acc); acc = fmaf(v1, wo[1], acc); acc = fmaf(v2, wo[2], acc);
        acc = fmaf(v3, wo[3], acc); acc = fmaf(v4, wo[4], acc); acc = fmaf(v5, wo[5], acc);
        X[base + (size_t)o * NHW] = gelu_f(acc);
    }
}

// ---------------------------------------------------------------- S1: forward W-DFT (plain activated input)
__global__ void __launch_bounds__(256) k_s1(const float* __restrict__ X, const float* __restrict__ D1,
                                            float* __restrict__ rz) {
    __shared__ float Xl[32][132];  // [k][row]
    __shared__ float Dl[32][100];  // [k][col]
    int t = threadIdx.x;
    int row0 = blockIdx.x * 128;
    int tn = t % 16, tm = t / 16;
    int r0 = tn * 8, c0 = tm * 6;
    float acc[8][6] = {};
    for (int kc = 0; kc < 256; kc += 32) {
        __syncthreads();
#pragma unroll
        for (int it = 0; it < 4; it++) {
            int slot = t + 256 * it;
            int r = slot >> 3, j4 = (slot & 7) * 4;
            float4 g = *(const float4*)&X[(size_t)(row0 + r) * 256 + kc + j4];
            Xl[j4 + 0][r] = g.x; Xl[j4 + 1][r] = g.y; Xl[j4 + 2][r] = g.z; Xl[j4 + 3][r] = g.w;
        }
#pragma unroll
        for (int it = 0; it < 3; it++) {
            int slot = t + 256 * it;
            int rr = slot / 24, c4 = (slot % 24) * 4;
            *(float4*)&Dl[rr][c4] = *(const float4*)&D1[(size_t)(kc + rr) * 96 + c4];
        }
        __syncthreads();
        for (int k = 0; k < 32; k++) {
            float a[8], d[6];
#pragma unroll
            for (int i = 0; i < 8; i++) a[i] = Xl[k][r0 + i];
#pragma unroll
            for (int j = 0; j < 6; j++) d[j] = Dl[k][c0 + j];
#pragma unroll
            for (int i = 0; i < 8; i++)
#pragma unroll
                for (int j = 0; j < 6; j++) acc[i][j] = fmaf(a[i], d[j], acc[i][j]);
        }
    }
#pragma unroll
    for (int i = 0; i < 8; i++) {
        size_t row = row0 + r0 + i;
#pragma unroll
        for (int j = 0; j < 6; j++) {
            int col = c0 + j;
            if (col < 84) rz[row * 84 + col] = acc[i][j];
        }
    }
}

// ---------------------------------------------------------------- S2: forward H-DFT
__global__ void __launch_bounds__(256) k_s2(const float* __restrict__ r1, const float* __restrict__ T1c,
                                            const float* __restrict__ T1s, float* __restrict__ xf) {
    int bc = blockIdx.x;
    int t = threadIdx.x;
    __shared__ float rl[32][88];
    __shared__ float tcl[32][48], tsl[32][48];
    int tkh = t / 11, tkw = t % 11;
    bool act = (t < 231);
    int kh0 = tkh * 2, kw0 = tkw * 4;
    float accr[2][4] = {}, acci[2][4] = {};
    const float* rp = r1 + (size_t)bc * 256 * 84;
    for (int hc = 0; hc < 256; hc += 32) {
        __syncthreads();
        for (int f = t; f < 32 * 88; f += 256) {
            int hl = f / 88, m = f % 88;
            rl[hl][m] = (m < 84) ? rp[(size_t)(hc + hl) * 84 + m] : 0.f;
        }
        for (int f = t; f < 32 * 48; f += 256) {
            int hl = f / 48, k = f % 48;
            tcl[hl][k] = T1c[(hc + hl) * 48 + k];
            tsl[hl][k] = T1s[(hc + hl) * 48 + k];
        }
        __syncthreads();
        if (act) {
            for (int hl = 0; hl < 32; hl++) {
                float c0 = tcl[hl][kh0], s0 = tsl[hl][kh0];
                float c1 = tcl[hl][kh0 + 1], s1v = tsl[hl][kh0 + 1];
#pragma unroll
                for (int j = 0; j < 4; j++) {
                    float arr = rl[hl][(kw0 + j) * 2], aii = rl[hl][(kw0 + j) * 2 + 1];
                    accr[0][j] = fmaf(arr, c0, fmaf(aii, s0, accr[0][j]));
                    acci[0][j] = fmaf(aii, c0, fmaf(-arr, s0, acci[0][j]));
                    accr[1][j] = fmaf(arr, c1, fmaf(aii, s1v, accr[1][j]));
                    acci[1][j] = fmaf(aii, c1, fmaf(-arr, s1v, acci[1][j]));
                }
            }
        }
    }
    if (act) {
        float* xp = xf + (size_t)bc * (PADM * 2);
#pragma unroll
        for (int i = 0; i < 2; i++)
#pragma unroll
            for (int j = 0; j < 4; j++) {
                int kw = kw0 + j;
                if (kw < 42) {
                    xp[((kh0 + i) * 42 + kw) * 2] = accr[i][j];
                    xp[((kh0 + i) * 42 + kw) * 2 + 1] = acci[i][j];
                }
            }
    }
}

// ---------------------------------------------------------------- S3: per-mode channel mix, native spec_w layout
__global__ void __launch_bounds__(256) k_s3(const float* __restrict__ xfb, const float* __restrict__ sw,
                                            float* __restrict__ ofb, int nbc) {
    int bx = blockIdx.x;
    int b = bx % nbc, mt = bx / nbc;
    int m0 = mt * 16;
    int t = threadIdx.x;
    __shared__ float2 xl[96][16];
    const float2* xx = (const float2*)xfb;
    for (int f = t; f < 1536; f += 256) {
        int i = f >> 4, ml = f & 15;
        int m = m0 + ml;
        float2 v = make_float2(0.f, 0.f);
        if (m < 1764) v = xx[(size_t)(b * 96 + i) * PADM + m];
        xl[i][ml] = v;
    }
    __syncthreads();
    int ml = t & 15, og = t >> 4;
    int m = m0 + ml;
    if (m >= 1764) return;
    float accr[6] = {}, acci[6] = {};
    const float2* wp = (const float2*)sw;
    for (int i = 0; i < 96; i++) {
        float2 xv = xl[i][ml];
#pragma unroll
        for (int j = 0; j < 6; j++) {
            int o = og * 6 + j;
            float2 wv = wp[(size_t)(i * 96 + o) * 1764 + m];
            accr[j] = fmaf(xv.x, wv.x, fmaf(-xv.y, wv.y, accr[j]));
            acci[j] = fmaf(xv.x, wv.y, fmaf(xv.y, wv.x, acci[j]));
        }
    }
    float2* op = (float2*)ofb;
#pragma unroll
    for (int j = 0; j < 6; j++) {
        int o = og * 6 + j;
        op[(size_t)(b * 96 + o) * PADM + m] = make_float2(accr[j], acci[j]);
    }
}

// ---------------------------------------------------------------- dense 1x1 conv (plain activated input)
__global__ void __launch_bounds__(256) k_dense(const float* __restrict__ X, const float* __restrict__ dw,
                                               const float* __restrict__ db, float* __restrict__ B) {
    __shared__ float Xl[32][132];
    __shared__ float Wl[32][100];
    __shared__ float bs[96];
    int t = threadIdx.x;
    int p0 = blockIdx.x * 128;
    int b = blockIdx.y;
    if (t < 96) bs[t] = db[t];
    int tn = t % 16, tm = t / 16;
    int n0 = tn * 8, m0 = tm * 6;
    float acc[8][6] = {};
    const float* xb = X + (size_t)b * 96 * NHW;
    for (int kc = 0; kc < 96; kc += 32) {
        __syncthreads();
#pragma unroll
        for (int it = 0; it < 4; it++) {
            int slot = t + 256 * it;
            int k = slot >> 5, j4 = (slot & 31) * 4;
            *(float4*)&Xl[k][j4] = *(const float4*)&xb[(size_t)(kc + k) * NHW + p0 + j4];
        }
#pragma unroll
        for (int it = 0; it < 3; it++) {
            int slot = t + 256 * it;
            int o = slot >> 3, j4 = (slot & 7) * 4;
            float4 g = *(const float4*)&dw[(size_t)o * 96 + kc + j4];
            Wl[j4 + 0][o] = g.x; Wl[j4 + 1][o] = g.y; Wl[j4 + 2][o] = g.z; Wl[j4 + 3][o] = g.w;
        }
        __syncthreads();
        for (int k = 0; k < 32; k++) {
            float a[8], wv[6];
#pragma unroll
            for (int i = 0; i < 8; i++) a[i] = Xl[k][n0 + i];
#pragma unroll
            for (int j = 0; j < 6; j++) wv[j] = Wl[k][m0 + j];
#pragma unroll
            for (int i = 0; i < 8; i++)
#pragma unroll
                for (int j = 0; j < 6; j++) acc[i][j] = fmaf(a[i], wv[j], acc[i][j]);
        }
    }
#pragma unroll
    for (int j = 0; j < 6; j++) {
        int o = m0 + j;
        float bv = bs[o];
        float* tp = B + ((size_t)b * 96 + o) * NHW + p0 + n0;
#pragma unroll
        for (int i = 0; i < 8; i++) tp[i] = acc[i][j] + bv;
    }
}

// ---------------------------------------------------------------- S5: fused inverse-H + inverse-W + depthwise
// + residual. Plane split into 2 h-halves per block. Chebyshev recurrence for all twiddles.
// Reads X (activated), B (dense); writes raw val into B; partial stats -> ps[bid].
__global__ void __launch_bounds__(256) k_s5(const float* __restrict__ X, float* __restrict__ B,
                                            const float* __restrict__ ofb,
                                            const float* __restrict__ T2c, const float* __restrict__ T2s,
                                            const float* __restrict__ lw, const float* __restrict__ lb,
                                            float2* __restrict__ ps) {
    int bid = blockIdx.x;
    int plane = bid >> 1, half = bid & 1;
    int o = plane % 96;
    int t = threadIdx.x;  // = w
    __shared__ float ofl[3528];
    __shared__ float xr[10][264];   // halo rows; interior at [4..259], edges [3],[260]
    __shared__ float zl[8][84];
    __shared__ float rs1[4], rs2[4];
    float l9[9];
#pragma unroll
    for (int j = 0; j < 9; j++) l9[j] = lw[o * 9 + j];
    float lbv = lb[o];
    const float* xp = X + (size_t)plane * NHW;
    float* tp = B + (size_t)plane * NHW;
    const float* op_ = ofb + (size_t)plane * (PADM * 2);
    for (int f = t; f < 3528; f += 256) ofl[f] = op_[f];
    if (t < 20) xr[t >> 1][(t & 1) ? 260 : 3] = 0.f;   // w edges are always zero-pad
    float cw1 = T2c[256 + t], sw1 = T2s[256 + t];      // cos/sin(2*pi*w/256)
    float s1 = 0.f, s2 = 0.f;
    int h0 = half * 128;
    for (int hc = h0; hc < h0 + 128; hc += 8) {
        __syncthreads();
        // halo interior: vectorized loads (zero OOB rows)
        for (int f = t; f < 640; f += 256) {
            int j = f >> 6, q = (f & 63) * 4;
            int hr = hc - 1 + j;
            float4 g = make_float4(0.f, 0.f, 0.f, 0.f);
            if (hr >= 0 && hr < 256) g = *(const float4*)&xp[(size_t)hr * 256 + q];
            *(float4*)&xr[j][4 + q] = g;
        }
        // fused inverse-H into zl via Chebyshev recurrence over kh
        for (int e = t; e < 336; e += 256) {
            int hl = e / 42, kw = e % 42;
            int h = hc + hl;
            float c1 = T2c[256 + h], s1v = T2s[256 + h];
            float twoc = 2.f * c1;
            float cp = 1.f, cc = c1, sp = 0.f, sc = s1v;
            float2 ov = *(const float2*)&ofl[kw * 2];
            float zr = ov.x, zi = ov.y;     // kh = 0 term (c=1, s=0)
#pragma unroll
            for (int kh = 1; kh < 42; kh++) {
                ov = *(const float2*)&ofl[(kh * 42 + kw) * 2];
                zr = fmaf(ov.x, cc, fmaf(-ov.y, sc, zr));
                zi = fmaf(ov.x, sc, fmaf(ov.y, cc, zi));
                float cn = fmaf(twoc, cc, -cp); cp = cc; cc = cn;
                float sn = fmaf(twoc, sc, -sp); sp = sc; sc = sn;
            }
            float fsc = (kw == 0) ? (1.0f / 65536.0f) : (2.0f / 65536.0f);
            zl[hl][2 * kw] = zr * fsc;
            zl[hl][2 * kw + 1] = zi * fsc;
        }
        __syncthreads();
        float twoc = 2.f * cw1;
#pragma unroll 1
        for (int hl = 0; hl < 8; hl++) {
            int h = hc + hl;
            // inverse-W via recurrence over kw, two acc chains
            float2 z0 = *(const float2*)&zl[hl][0];
            float acc0 = z0.x, acc1 = 0.f;
            float cp = 1.f, cc = cw1, sp = 0.f, sc = sw1;
#pragma unroll
            for (int k = 1; k < 42; k++) {
                float2 zz = *(const float2*)&zl[hl][2 * k];
                if (k & 1) acc1 = fmaf(zz.x, cc, fmaf(-zz.y, sc, acc1));
                else       acc0 = fmaf(zz.x, cc, fmaf(-zz.y, sc, acc0));
                float cn = fmaf(twoc, cc, -cp); cp = cc; cc = cn;
                float sn = fmaf(twoc, sc, -sp); sp = sc; sc = sn;
            }
            float acc = acc0 + acc1;
            float dv = tp[(size_t)h * 256 + t];
            float dwv = lbv;
#pragma unroll
            for (int a = 0; a < 3; a++)
#pragma unroll
                for (int bq = 0; bq < 3; bq++) dwv = fmaf(xr[hl + a][3 + t + bq], l9[a * 3 + bq], dwv);
            float xc = xr[hl + 1][4 + t];
            float val = xc + 0.5f * (acc + dv + dwv);
            tp[(size_t)h * 256 + t] = val;
            s1 += val;
            s2 = fmaf(val, val, s2);
        }
    }
    for (int off2 = 32; off2 > 0; off2 >>= 1) {
        s1 += __shfl_down(s1, off2);
        s2 += __shfl_down(s2, off2);
    }
    int wid = t >> 6, lane = t & 63;
    if (lane == 0) { rs1[wid] = s1; rs2[wid] = s2; }
    __syncthreads();
    if (t == 0) ps[bid] = make_float2(rs1[0] + rs1[1] + rs1[2] + rs1[3], rs2[0] + rs2[1] + rs2[2] + rs2[3]);
}

// ---------------------------------------------------------------- stats -> per-(b,c) affine (sc, sh)
__global__ void k_stats(const float2* __restrict__ ps, const float* __restrict__ ng,
                        const float* __restrict__ nb, float2* __restrict__ nrm, int n) {
    int i = blockIdx.x * 64 + threadIdx.x;
    if (i >= n) return;
    int c = i % 96, b = i / 96, g = c >> 4;
    float s = 0.f, q = 0.f;
    int base = (b * 96 + g * 16) * 2;
#pragma unroll
    for (int j = 0; j < 32; j++) { float2 v = ps[base + j]; s += v.x; q += v.y; }
    const float inv_n = 1.0f / 1048576.0f;
    float mean = s * inv_n;
    float var = q * inv_n - mean * mean;
    float rstd = rsqrtf(var + 1e-5f);
    float sc = rstd * ng[c];
    nrm[i] = make_float2(sc, nb[c] - mean * sc);
}

// ---------------------------------------------------------------- act: X = gelu(affine(val))  (memory-bound)
__global__ void __launch_bounds__(256) k_act(const float* __restrict__ V, const float2* __restrict__ nrm,
                                             float* __restrict__ X, int total4) {
    int idx = blockIdx.x * 256 + threadIdx.x;
    int stride = gridDim.x * 256;
    for (; idx < total4; idx += stride) {
        float2 nv = nrm[idx >> 14];   // 16384 float4 per plane
        float4 v = ((const float4*)V)[idx];
        float4 r;
        r.x = gelu_f(fmaf(v.x, nv.x, nv.y));
        r.y = gelu_f(fmaf(v.y, nv.x, nv.y));
        r.z = gelu_f(fmaf(v.z, nv.x, nv.y));
        r.w = gelu_f(fmaf(v.w, nv.x, nv.y));
        ((float4*)X)[idx] = r;
    }
}

// ---------------------------------------------------------------- out-proj + clip (plain activated input)
__global__ void __launch_bounds__(256) k_out(const float* __restrict__ X, const float* __restrict__ up,
                                             const float* __restrict__ opw, const float* __restrict__ opb,
                                             float* __restrict__ out, int b0) {
    __shared__ float wl[288];
    int t = threadIdx.x;
    int br = blockIdx.x >> 8;
    for (int f = t; f < 288; f += 256) wl[f] = opw[f];
    __syncthreads();
    int p = (blockIdx.x & 255) * 256 + t;
    const float* xp = X + (size_t)br * 96 * NHW + p;
    float a0 = opb[0], a1 = opb[1], a2 = opb[2];
    for (int i = 0; i < 96; i++) {
        float xv = xp[(size_t)i * NHW];
        a0 = fmaf(xv, wl[i], a0);
        a1 = fmaf(xv, wl[96 + i], a1);
        a2 = fmaf(xv, wl[192 + i], a2);
    }
    int b = b0 + br;
#pragma unroll
    for (int o = 0; o < 3; o++) {
        float av = (o == 0) ? a0 : ((o == 1) ? a1 : a2);
        size_t idx = ((size_t)b * 3 + o) * NHW + p;
        float v = up[idx] + av;
        out[idx] = fminf(fmaxf(v, 0.0f), 1.0f);
    }
}

extern "C" void kernel_launch(void* const* d_in, const int* in_sizes, int n_in,
                              void* d_out, int out_size, void* d_ws, size_t ws_size,
                              hipStream_t stream) {
    const float* up = (const float*)d_in[0];
    const float* noise = (const float*)d_in[1];
    const float* ipw = (const float*)d_in[2];
    const float* ipb = (const float*)d_in[3];
    const float* specw = (const float*)d_in[4];
    const float* dw = (const float*)d_in[5];
    const float* db = (const float*)d_in[6];
    const float* lw = (const float*)d_in[7];
    const float* lb = (const float*)d_in[8];
    const float* ng = (const float*)d_in[9];
    const float* nb = (const float*)d_in[10];
    const float* opw = (const float*)d_in[11];
    const float* opb = (const float*)d_in[12];
    float* out = (float*)d_out;

    // adaptive batch chunking: footprint(nbc) in floats
    auto needf = [](size_t nbc) -> size_t {
        return nbc * (2ull * 6291456 + 2064384 + 2ull * 344064 + 384 + 192) + 70656ull;
    };
    int nbc = 8;
    while (nbc > 1 && needf(nbc) * 4ull > ws_size) nbc >>= 1;
    if (needf(nbc) * 4ull > ws_size) return;  // even 1-batch doesn't fit: fail visibly

    float* ws = (float*)d_ws;
    float* X   = ws;                               // nbc*6291456  (activated)
    float* B   = X + (size_t)nbc * 6291456;        // nbc*6291456  (dense out / raw val)
    float* rz  = B + (size_t)nbc * 6291456;        // nbc*2064384
    float* xfb = rz + (size_t)nbc * 2064384;       // nbc*344064
    float* ofb = xfb + (size_t)nbc * 344064;       // nbc*344064
    float* ps  = ofb + (size_t)nbc * 344064;       // nbc*384 (nbc*192 float2, 2 per plane)
    float* nrm = ps + (size_t)nbc * 384;           // nbc*192 (nbc*96 float2)
    float* D1  = nrm + (size_t)nbc * 192;          // 24576
    float* T1c = D1 + 24576;                       // 12288
    float* T1s = T1c + 12288;                      // 12288
    float* T2c = T1s + 12288;                      // 10752
    float* T2s = T2c + 10752;                      // 10752

    k_tables<<<48, 256, 0, stream>>>(D1, T1c, T1s, T2c, T2s);

    for (int b0 = 0; b0 < 8; b0 += nbc) {
        k_in<<<nbc * 256, 256, 0, stream>>>(up, noise, ipw, ipb, X, b0);
        for (int l = 0; l < 4; l++) {
            k_s1<<<nbc * 192, 256, 0, stream>>>(X, D1, rz);
            k_s2<<<nbc * 96, 256, 0, stream>>>(rz, T1c, T1s, xfb);
            k_s3<<<111 * nbc, 256, 0, stream>>>(xfb, specw, ofb, nbc);
            k_dense<<<dim3(512, nbc), 256, 0, stream>>>(X, dw + (size_t)l * 9216, db + (size_t)l * 96, B);
            k_s5<<<nbc * 192, 256, 0, stream>>>(X, B, ofb, T2c, T2s,
                                                lw + (size_t)l * 864, lb + (size_t)l * 96, (float2*)ps);
            k_stats<<<(nbc * 96 + 63) / 64, 64, 0, stream>>>((const float2*)ps, ng + (size_t)l * 96,
                                                             nb + (size_t)l * 96, (float2*)nrm, nbc * 96);
            k_act<<<4096, 256, 0, stream>>>(B, (const float2*)nrm, X, nbc * 96 * 16384);
        }
        k_out<<<nbc * 256, 256, 0, stream>>>(X, up, opw, opb, out, b0);
    }
}